// Round 18
// baseline (421.987 us; speedup 1.0000x reference)
//
#include <hip/hip_runtime.h>
#include <hip/hip_bf16.h>

#define NUM_USERS 100000
#define NUM_ITEMS 50000
#define N_NODES   150000
#define DIM       64
#define N_LAYERS  3
#define N_QU      1024
#define N_QI      20000
#define N_QTOT    (N_QU + N_QI)
#define SLOTS     80

#define BIN_SHIFT 9
#define BIN_W     512
#define NBINS     ((N_NODES + BIN_W - 1) >> BIN_SHIFT)   // 293
#define BIN_CAP   17472                                   // mean 16382 + 8.5 sigma
#define S1_BATCH  2048                                    // 256 thr x 8 edges

typedef __attribute__((ext_vector_type(8))) short bf16x8;
typedef __attribute__((ext_vector_type(4))) float f32x4;
typedef __attribute__((ext_vector_type(8))) unsigned short u16x8;

__device__ __forceinline__ short f2bf(float x) {   // RNE float -> bf16 bits
    unsigned u = __float_as_uint(x);
    u += 0x7FFF + ((u >> 16) & 1);
    return (short)(u >> 16);
}
__device__ __forceinline__ float bf2f(unsigned short u) {
    return __uint_as_float((unsigned)u << 16);
}

// ---------------------------------------------------------------------------
// init: h0 = bf16(concat(user_emb, item_emb)); 8 dims per thread
// ---------------------------------------------------------------------------
__global__ void init_h0(const float* __restrict__ ue, const float* __restrict__ ie,
                        unsigned short* __restrict__ h0) {
    const size_t n8   = (size_t)N_NODES * DIM / 8;     // 1.2M
    const size_t uend = (size_t)NUM_USERS * DIM / 8;
    size_t stride = (size_t)gridDim.x * blockDim.x;
    for (size_t i = (size_t)blockIdx.x * blockDim.x + threadIdx.x; i < n8; i += stride) {
        const float4* s = (i < uend) ? ((const float4*)ue) + i * 2
                                     : ((const float4*)ie) + (i - uend) * 2;
        float4 a = s[0], b = s[1];
        ushort4 lo, hi;
        lo.x = (unsigned short)f2bf(a.x); lo.y = (unsigned short)f2bf(a.y);
        lo.z = (unsigned short)f2bf(a.z); lo.w = (unsigned short)f2bf(a.w);
        hi.x = (unsigned short)f2bf(b.x); hi.y = (unsigned short)f2bf(b.y);
        hi.z = (unsigned short)f2bf(b.z); hi.w = (unsigned short)f2bf(b.w);
        ((ushort4*)h0)[i * 2]     = lo;
        ((ushort4*)h0)[i * 2 + 1] = hi;
    }
}

// ---------------------------------------------------------------------------
// queried-node list: users, then items+NUM_USERS (duplicates benign)
// ---------------------------------------------------------------------------
__global__ void build_qlist(const int* __restrict__ users, const int* __restrict__ items,
                            int* __restrict__ qlist) {
    int i = blockIdx.x * blockDim.x + threadIdx.x;
    if (i < N_QU) qlist[i] = users[i];
    else if (i < N_QTOT) qlist[i] = NUM_USERS + items[i - N_QU];
}

// ---------------------------------------------------------------------------
// S1 coarse partition: one block per 2048-edge batch (2344 blocks -> ~9/CU,
// full wave residency; Round 17 fix: 4096-edge batches gave only 42% occ).
// LDS histogram over 293 coarse bins, ONE global atomic per non-empty bin
// reserves a range, then edges scatter to binned[] with LDS cursors.
// Packing: w0 = (dst_local:9 << 18) | src:18, w1 = val bits.
// ---------------------------------------------------------------------------
__global__ __launch_bounds__(256) void s1_coarse(
        const int* __restrict__ src, const int* __restrict__ dst,
        const float* __restrict__ vals, int* __restrict__ gcnt,
        int2* __restrict__ binned, int n) {
    __shared__ int dcache[S1_BATCH];
    __shared__ int hist[NBINS];
    __shared__ int base[NBINS];
    const int t  = threadIdx.x;
    const int b0 = blockIdx.x * S1_BATCH;

    for (int i = t; i < NBINS; i += 256) hist[i] = 0;
    __syncthreads();

    // phase A: load dst batch, LDS count per bin
    #pragma unroll
    for (int k = 0; k < S1_BATCH / 256; ++k) {
        int e = b0 + k * 256 + t;
        int d = (e < n) ? dst[e] : -1;
        dcache[k * 256 + t] = d;
        if (d >= 0) atomicAdd(&hist[d >> BIN_SHIFT], 1);
    }
    __syncthreads();

    // phase B: reserve global ranges (one device atomic per non-empty bin)
    for (int i = t; i < NBINS; i += 256) {
        int c = hist[i];
        base[i] = (c > 0) ? atomicAdd(&gcnt[i], c) : 0;
        hist[i] = 0;                     // reuse as cursor
    }
    __syncthreads();

    // phase C: scatter packed edges into binned[]
    #pragma unroll
    for (int k = 0; k < S1_BATCH / 256; ++k) {
        int e = b0 + k * 256 + t;
        if (e < n) {
            int d   = dcache[k * 256 + t];
            int bin = d >> BIN_SHIFT;
            int local = atomicAdd(&hist[bin], 1);
            int slot  = base[bin] + local;
            if (slot < BIN_CAP) {
                int w0 = ((d & (BIN_W - 1)) << 18) | src[e];
                binned[(size_t)bin * BIN_CAP + slot] =
                    make_int2(w0, __float_as_int(vals[e]));
            }
        }
    }
}

// ---------------------------------------------------------------------------
// S2 fine sort: one block per bin, 1024 threads (16 waves -> 18 waves/CU at
// 293 blocks; 512 thr gave only 8). Streams the bin's packed edges
// (coalesced) and distributes into node*SLOTS buckets via LDS cursors.
// Writes cnt[] for every node -> no cnt memset.
// ---------------------------------------------------------------------------
__global__ __launch_bounds__(1024) void s2_fine(
        const int* __restrict__ gcnt, const int2* __restrict__ binned,
        int* __restrict__ cnt, int2* __restrict__ buckets) {
    __shared__ int cursor[BIN_W];
    const int bin = blockIdx.x;
    const int t   = threadIdx.x;
    if (t < BIN_W) cursor[t] = 0;
    __syncthreads();

    int m = gcnt[bin]; if (m > BIN_CAP) m = BIN_CAP;
    const int2* bp = &binned[(size_t)bin * BIN_CAP];
    for (int i = t; i < m; i += 1024) {
        int2 p  = bp[i];
        int  dl = ((unsigned)p.x) >> 18;
        int  local = atomicAdd(&cursor[dl], 1);
        if (local < SLOTS) {
            int node = (bin << BIN_SHIFT) + dl;
            buckets[(size_t)node * SLOTS + local] =
                make_int2(p.x & 0x3FFFF, p.y);
        }
    }
    __syncthreads();

    if (t < BIN_W) {
        int node = (bin << BIN_SHIFT) + t;
        if (node < N_NODES) {
            int c = cursor[t]; if (c > SLOTS) c = SLOTS;
            cnt[node] = c;
        }
    }
}

// ---------------------------------------------------------------------------
// bucket SpMM gather, bf16 x/y, f32 accumulate: 8 lanes per dst node,
// ushort8 (16 B) per lane -> 128 B coalesced row gathers; 8 nodes per wave.
// 4 edges/iter, cnt prefetched one node ahead. If list != null, only nodes
// in list[0..count) are computed (last layer: queried rows only).
// ---------------------------------------------------------------------------
__global__ __launch_bounds__(256) void spmm_bucket_bf16(
        const int* __restrict__ cnt, const int2* __restrict__ buckets,
        const unsigned short* __restrict__ x, unsigned short* __restrict__ y,
        const int* __restrict__ list, int count) {
    int lane8   = threadIdx.x & 7;
    int group   = (int)((blockIdx.x * blockDim.x + threadIdx.x) >> 3);
    int ngroups = (int)((gridDim.x * blockDim.x) >> 3);
    const u16x8* x8 = (const u16x8*)x;

    int i = group;
    if (i >= count) return;
    int node_n = list ? list[i] : i;
    int m_n = cnt[node_n];

    for (; i < count; i += ngroups) {
        int node = node_n;
        int m = m_n; if (m > SLOTS) m = SLOTS;
        int j = i + ngroups;
        if (j < count) { node_n = list ? list[j] : j; m_n = cnt[node_n]; }

        const int2* row  = &buckets[(size_t)node * SLOTS];
        const int4* row2 = (const int4*)row;            // 2 packed edges per int4
        float r[8];
        #pragma unroll
        for (int k = 0; k < 8; ++k) r[k] = 0.0f;

        int e = 0;
        for (; e + 4 <= m; e += 4) {
            int4 pa = row2[(e >> 1)];
            int4 pb = row2[(e >> 1) + 1];
            u16x8 x0 = x8[(size_t)pa.x * 8 + lane8];
            u16x8 x1 = x8[(size_t)pa.z * 8 + lane8];
            u16x8 x2 = x8[(size_t)pb.x * 8 + lane8];
            u16x8 x3 = x8[(size_t)pb.z * 8 + lane8];
            float v0 = __int_as_float(pa.y), v1 = __int_as_float(pa.w);
            float v2 = __int_as_float(pb.y), v3 = __int_as_float(pb.w);
            #pragma unroll
            for (int k = 0; k < 8; ++k) r[k] += v0 * bf2f(x0[k]);
            #pragma unroll
            for (int k = 0; k < 8; ++k) r[k] += v1 * bf2f(x1[k]);
            #pragma unroll
            for (int k = 0; k < 8; ++k) r[k] += v2 * bf2f(x2[k]);
            #pragma unroll
            for (int k = 0; k < 8; ++k) r[k] += v3 * bf2f(x3[k]);
        }
        if (e + 2 <= m) {                               // e is even here
            int4 pa = row2[(e >> 1)];
            u16x8 x0 = x8[(size_t)pa.x * 8 + lane8];
            u16x8 x1 = x8[(size_t)pa.z * 8 + lane8];
            float v0 = __int_as_float(pa.y), v1 = __int_as_float(pa.w);
            #pragma unroll
            for (int k = 0; k < 8; ++k) r[k] += v0 * bf2f(x0[k]);
            #pragma unroll
            for (int k = 0; k < 8; ++k) r[k] += v1 * bf2f(x1[k]);
            e += 2;
        }
        if (e < m) {
            int2 p = row[e];
            float v = __int_as_float(p.y);
            u16x8 x0 = x8[(size_t)p.x * 8 + lane8];
            #pragma unroll
            for (int k = 0; k < 8; ++k) r[k] += v * bf2f(x0[k]);
        }

        u16x8 o;
        #pragma unroll
        for (int k = 0; k < 8; ++k) o[k] = (unsigned short)f2bf(r[k]);
        ((u16x8*)y)[(size_t)node * 8 + lane8] = o;
    }
}

// ---------------------------------------------------------------------------
// prep: packed[q] = bf16( (e0 + h1 + h2 + h3) * 0.25 ) for all 21024 queried
// positions (users first, then items). 8 lanes per row, 8 dims per lane.
// ---------------------------------------------------------------------------
__global__ __launch_bounds__(256) void prep_packed(
        const float* __restrict__ ue, const float* __restrict__ ie,
        const unsigned short* __restrict__ h1, const unsigned short* __restrict__ h2,
        const unsigned short* __restrict__ h3, const int* __restrict__ users,
        const int* __restrict__ items, unsigned short* __restrict__ packed) {
    int idx = blockIdx.x * blockDim.x + threadIdx.x;
    if (idx >= N_QTOT * 8) return;
    int q = idx >> 3, lane = idx & 7;

    const float* e0;
    size_t hoff;
    if (q < N_QU) {
        int u = users[q];
        e0   = &ue[(size_t)u * DIM];
        hoff = (size_t)u * DIM;
    } else {
        int it = items[q - N_QU];
        e0   = &ie[(size_t)it * DIM];
        hoff = (size_t)(NUM_USERS + it) * DIM;
    }
    int d0 = lane * 8;
    const float4* s0 = (const float4*)&e0[d0];
    float4 a0 = s0[0], a1 = s0[1];
    u16x8 b1 = *(const u16x8*)&h1[hoff + d0];
    u16x8 b2 = *(const u16x8*)&h2[hoff + d0];
    u16x8 b3 = *(const u16x8*)&h3[hoff + d0];

    float v[8];
    v[0] = a0.x; v[1] = a0.y; v[2] = a0.z; v[3] = a0.w;
    v[4] = a1.x; v[5] = a1.y; v[6] = a1.z; v[7] = a1.w;
    u16x8 o;
    #pragma unroll
    for (int k = 0; k < 8; ++k) {
        float t = (v[k] + bf2f(b1[k]) + bf2f(b2[k]) + bf2f(b3[k])) * 0.25f;
        o[k] = (unsigned short)f2bf(t);
    }
    *(u16x8*)&packed[(size_t)q * DIM + d0] = o;
}

// ---------------------------------------------------------------------------
// ratings = sigmoid( packedU @ packedT^T ) via bf16 MFMA.
// ---------------------------------------------------------------------------
__global__ __launch_bounds__(256) void rating_mfma(
        const unsigned short* __restrict__ packed, float* __restrict__ out) {
    __shared__ short Ut[64 * 72];     //  9216 B
    __shared__ short Tt[256 * 72];    // 36864 B
    const int bj = blockIdx.x;        // item tile (256 wide)
    const int bi = blockIdx.y;        // user tile (64 wide)
    const int tid = threadIdx.x;

    {
        int r = tid >> 2, c16 = (tid & 3) * 16;
        const bf16x8* s = (const bf16x8*)&packed[(size_t)(bi * 64 + r) * DIM + c16];
        *(bf16x8*)&Ut[r * 72 + c16]     = s[0];
        *(bf16x8*)&Ut[r * 72 + c16 + 8] = s[1];
    }

    #pragma unroll
    for (int p = 0; p < 4; ++p) {
        int r = (tid >> 2) + p * 64, c16 = (tid & 3) * 16;
        int jg = bj * 256 + r;
        bf16x8 lo = (bf16x8)(short)0, hi = (bf16x8)(short)0;
        if (jg < N_QI) {
            const bf16x8* s = (const bf16x8*)&packed[(size_t)(N_QU + jg) * DIM + c16];
            lo = s[0]; hi = s[1];
        }
        *(bf16x8*)&Tt[r * 72 + c16]     = lo;
        *(bf16x8*)&Tt[r * 72 + c16 + 8] = hi;
    }
    __syncthreads();

    const int wv = tid >> 6, lane = tid & 63;
    const int lr = lane & 15, kq = lane >> 4;

    f32x4 c[4][4];
    #pragma unroll
    for (int mr = 0; mr < 4; ++mr)
        #pragma unroll
        for (int nr = 0; nr < 4; ++nr)
            c[mr][nr] = (f32x4)(0.0f);

    #pragma unroll
    for (int kb = 0; kb < 2; ++kb) {
        bf16x8 a[4], b[4];
        #pragma unroll
        for (int mr = 0; mr < 4; ++mr)
            a[mr] = *(const bf16x8*)&Ut[(mr * 16 + lr) * 72 + (kb * 4 + kq) * 8];
        #pragma unroll
        for (int nr = 0; nr < 4; ++nr)
            b[nr] = *(const bf16x8*)&Tt[(wv * 64 + nr * 16 + lr) * 72 + (kb * 4 + kq) * 8];
        #pragma unroll
        for (int mr = 0; mr < 4; ++mr)
            #pragma unroll
            for (int nr = 0; nr < 4; ++nr)
                c[mr][nr] = __builtin_amdgcn_mfma_f32_16x16x32_bf16(a[mr], b[nr], c[mr][nr], 0, 0, 0);
    }

    #pragma unroll
    for (int mr = 0; mr < 4; ++mr) {
        int rowg = bi * 64 + mr * 16 + kq * 4;
        #pragma unroll
        for (int nr = 0; nr < 4; ++nr) {
            int colg = bj * 256 + wv * 64 + nr * 16 + lr;
            if (colg < N_QI) {
                #pragma unroll
                for (int q = 0; q < 4; ++q) {
                    float z = c[mr][nr][q];
                    out[(size_t)(rowg + q) * N_QI + colg] = 1.0f / (1.0f + __expf(-z));
                }
            }
        }
    }
}

// ---------------------------------------------------------------------------
extern "C" void kernel_launch(void* const* d_in, const int* in_sizes, int n_in,
                              void* d_out, int out_size, void* d_ws, size_t ws_size,
                              hipStream_t stream) {
    const float* user_emb  = (const float*)d_in[0];
    const float* item_emb  = (const float*)d_in[1];
    const int*   edge_src  = (const int*)d_in[2];
    const int*   edge_dst  = (const int*)d_in[3];
    const float* edge_vals = (const float*)d_in[4];
    const int*   users     = (const int*)d_in[5];
    const int*   items     = (const int*)d_in[6];
    float*       out       = (float*)d_out;
    int n_edges = in_sizes[2];

    const size_t nodeElems = (size_t)N_NODES * DIM;   // 9.6M elems

    // workspace: 4 bf16 node buffers + cnt + buckets + qlist + packed + gcnt.
    // binned (41 MB) ALIASES h1..h3 (57.6 MB) -- dead before spmm writes h1.
    unsigned short* h0 = (unsigned short*)d_ws;
    unsigned short* h1 = h0 + nodeElems;
    unsigned short* h2 = h1 + nodeElems;
    unsigned short* h3 = h2 + nodeElems;
    int*  cnt     = (int*)(h3 + nodeElems);           // 150000 ints
    int2* buckets = (int2*)(cnt + N_NODES);           // 12M int2 = 96 MB
    int*  qlist   = (int*)(buckets + (size_t)N_NODES * SLOTS);   // 21024 ints
    unsigned short* packed = (unsigned short*)(qlist + N_QTOT);  // 21024*64 bf16
    int*  gcnt    = (int*)(packed + (size_t)N_QTOT * DIM);       // 293 ints
    int2* binned  = (int2*)h1;                        // scratch alias, 41 MB

    (void)hipMemsetAsync(gcnt, 0, NBINS * sizeof(int), stream);
    init_h0<<<2048, 256, 0, stream>>>(user_emb, item_emb, h0);
    build_qlist<<<(N_QTOT + 255) / 256, 256, 0, stream>>>(users, items, qlist);

    // two-level CSR build: coarse bins (aggregated global atomics) -> fine LDS sort
    int nbatches = (n_edges + S1_BATCH - 1) / S1_BATCH;
    s1_coarse<<<nbatches, 256, 0, stream>>>(edge_src, edge_dst, edge_vals,
                                            gcnt, binned, n_edges);
    s2_fine<<<NBINS, 1024, 0, stream>>>(gcnt, binned, cnt, buckets);

    spmm_bucket_bf16<<<2048, 256, 0, stream>>>(cnt, buckets, h0, h1, nullptr, N_NODES);
    spmm_bucket_bf16<<<2048, 256, 0, stream>>>(cnt, buckets, h1, h2, nullptr, N_NODES);
    spmm_bucket_bf16<<<2048, 256, 0, stream>>>(cnt, buckets, h2, h3, qlist, N_QTOT);

    prep_packed<<<(N_QTOT * 8 + 255) / 256, 256, 0, stream>>>(
        user_emb, item_emb, h1, h2, h3, users, items, packed);

    dim3 grid((N_QI + 255) / 256, N_QU / 64);
    rating_mfma<<<grid, 256, 0, stream>>>(packed, out);
}

// Round 19
// 360.748 us; speedup vs baseline: 1.1698x; 1.1698x over previous
//
#include <hip/hip_runtime.h>
#include <hip/hip_bf16.h>

#define NUM_USERS 100000
#define NUM_ITEMS 50000
#define N_NODES   150000
#define DIM       64
#define N_LAYERS  3
#define N_QU      1024
#define N_QI      20000
#define N_QTOT    (N_QU + N_QI)
#define SLOTS     80

#define BIN_SHIFT 9
#define BIN_W     512
#define NBINS     ((N_NODES + BIN_W - 1) >> BIN_SHIFT)   // 293
#define BIN_CAP   17472                                   // mean 16382 + 8.5 sigma
#define S1_BATCH  4096                                    // 256 thr x 16 edges

typedef __attribute__((ext_vector_type(8))) short bf16x8;
typedef __attribute__((ext_vector_type(4))) float f32x4;
typedef __attribute__((ext_vector_type(8))) unsigned short u16x8;

__device__ __forceinline__ short f2bf(float x) {   // RNE float -> bf16 bits
    unsigned u = __float_as_uint(x);
    u += 0x7FFF + ((u >> 16) & 1);
    return (short)(u >> 16);
}
__device__ __forceinline__ float bf2f(unsigned short u) {
    return __uint_as_float((unsigned)u << 16);
}

// ---------------------------------------------------------------------------
// init: h0 = bf16(concat(user_emb, item_emb)); 8 dims per thread
// ---------------------------------------------------------------------------
__global__ void init_h0(const float* __restrict__ ue, const float* __restrict__ ie,
                        unsigned short* __restrict__ h0) {
    const size_t n8   = (size_t)N_NODES * DIM / 8;     // 1.2M
    const size_t uend = (size_t)NUM_USERS * DIM / 8;
    size_t stride = (size_t)gridDim.x * blockDim.x;
    for (size_t i = (size_t)blockIdx.x * blockDim.x + threadIdx.x; i < n8; i += stride) {
        const float4* s = (i < uend) ? ((const float4*)ue) + i * 2
                                     : ((const float4*)ie) + (i - uend) * 2;
        float4 a = s[0], b = s[1];
        ushort4 lo, hi;
        lo.x = (unsigned short)f2bf(a.x); lo.y = (unsigned short)f2bf(a.y);
        lo.z = (unsigned short)f2bf(a.z); lo.w = (unsigned short)f2bf(a.w);
        hi.x = (unsigned short)f2bf(b.x); hi.y = (unsigned short)f2bf(b.y);
        hi.z = (unsigned short)f2bf(b.z); hi.w = (unsigned short)f2bf(b.w);
        ((ushort4*)h0)[i * 2]     = lo;
        ((ushort4*)h0)[i * 2 + 1] = hi;
    }
}

// ---------------------------------------------------------------------------
// queried-node list: users, then items+NUM_USERS (duplicates benign)
// ---------------------------------------------------------------------------
__global__ void build_qlist(const int* __restrict__ users, const int* __restrict__ items,
                            int* __restrict__ qlist) {
    int i = blockIdx.x * blockDim.x + threadIdx.x;
    if (i < N_QU) qlist[i] = users[i];
    else if (i < N_QTOT) qlist[i] = NUM_USERS + items[i - N_QU];
}

// ---------------------------------------------------------------------------
// S1 coarse partition with LDS bin-sort (Round 18 lesson: the 8B random
// scatter had 3x write amplification; occupancy was NOT the limiter).
// Per 4096-edge block: (A) LDS histogram, (B) block scan -> pfx + one global
// atomic per bin -> base, (C) stage edges bin-sorted in LDS, (D) wave-per-bin
// burst copy to global: consecutive lanes -> consecutive addresses.
// Packing: w0 = (dst_local:9 << 18) | src:18, w1 = val bits.
// ---------------------------------------------------------------------------
__global__ __launch_bounds__(256) void s1_coarse(
        const int* __restrict__ src, const int* __restrict__ dst,
        const float* __restrict__ vals, int* __restrict__ gcnt,
        int2* __restrict__ binned, int n) {
    __shared__ int2 staging[S1_BATCH];   // 32 KB, bin-sorted packed edges
    __shared__ int  hist[NBINS];         // counts, then cursors
    __shared__ int  base[NBINS];         // global base per bin
    __shared__ int  pfx[NBINS];          // block-local exclusive prefix
    __shared__ int  part[256];           // scan scratch
    const int t  = threadIdx.x;
    const int b0 = blockIdx.x * S1_BATCH;
    const int n4 = n >> 2;
    const int i4base = b0 >> 2;
    const int4*   d4 = (const int4*)dst;
    const int4*   s4 = (const int4*)src;
    const float4* v4 = (const float4*)vals;

    for (int i = t; i < NBINS; i += 256) hist[i] = 0;
    __syncthreads();

    // --- phase A: histogram dsts per bin (vectorized stream) ---
    #pragma unroll
    for (int k = 0; k < 4; ++k) {
        int i4 = i4base + k * 256 + t;
        if (i4 < n4) {
            int4 d = d4[i4];
            atomicAdd(&hist[d.x >> BIN_SHIFT], 1);
            atomicAdd(&hist[d.y >> BIN_SHIFT], 1);
            atomicAdd(&hist[d.z >> BIN_SHIFT], 1);
            atomicAdd(&hist[d.w >> BIN_SHIFT], 1);
        }
    }
    for (int e = (n & ~3) + t; e < n; e += 256)               // scalar tail
        if (e >= b0 && e < b0 + S1_BATCH)
            atomicAdd(&hist[dst[e] >> BIN_SHIFT], 1);
    __syncthreads();

    // --- phase B1: block-local exclusive scan of hist -> pfx ---
    {
        int i0 = 2 * t, i1 = 2 * t + 1;
        int h0v = (i0 < NBINS) ? hist[i0] : 0;
        int h1v = (i1 < NBINS) ? hist[i1] : 0;
        int s = h0v + h1v;
        part[t] = s;
        __syncthreads();
        int x = s;
        for (int off = 1; off < 256; off <<= 1) {
            int y = (t >= off) ? part[t - off] : 0;
            __syncthreads();
            x += y;
            part[t] = x;
            __syncthreads();
        }
        int exc = x - s;
        if (i0 < NBINS) pfx[i0] = exc;
        if (i1 < NBINS) pfx[i1] = exc + h0v;
    }
    __syncthreads();

    // --- phase B2: reserve global ranges; reset hist to cursors ---
    for (int i = t; i < NBINS; i += 256) {
        int c = hist[i];
        base[i] = (c > 0) ? atomicAdd(&gcnt[i], c) : 0;
    }
    __syncthreads();
    for (int i = t; i < NBINS; i += 256) hist[i] = 0;
    __syncthreads();

    // --- phase C: stage packed edges bin-sorted into LDS ---
    #pragma unroll
    for (int k = 0; k < 4; ++k) {
        int i4 = i4base + k * 256 + t;
        if (i4 < n4) {
            int4   d = d4[i4];
            int4   s = s4[i4];
            float4 v = v4[i4];
            int bin, loc;
            bin = d.x >> BIN_SHIFT; loc = atomicAdd(&hist[bin], 1);
            staging[pfx[bin] + loc] = make_int2(((d.x & (BIN_W-1)) << 18) | s.x, __float_as_int(v.x));
            bin = d.y >> BIN_SHIFT; loc = atomicAdd(&hist[bin], 1);
            staging[pfx[bin] + loc] = make_int2(((d.y & (BIN_W-1)) << 18) | s.y, __float_as_int(v.y));
            bin = d.z >> BIN_SHIFT; loc = atomicAdd(&hist[bin], 1);
            staging[pfx[bin] + loc] = make_int2(((d.z & (BIN_W-1)) << 18) | s.z, __float_as_int(v.z));
            bin = d.w >> BIN_SHIFT; loc = atomicAdd(&hist[bin], 1);
            staging[pfx[bin] + loc] = make_int2(((d.w & (BIN_W-1)) << 18) | s.w, __float_as_int(v.w));
        }
    }
    for (int e = (n & ~3) + t; e < n; e += 256)               // scalar tail
        if (e >= b0 && e < b0 + S1_BATCH) {
            int d = dst[e];
            int bin = d >> BIN_SHIFT;
            int loc = atomicAdd(&hist[bin], 1);
            staging[pfx[bin] + loc] = make_int2(((d & (BIN_W-1)) << 18) | src[e], __float_as_int(vals[e]));
        }
    __syncthreads();

    // --- phase D: wave-per-bin coalesced burst copy LDS -> global ---
    {
        int wid = t >> 6, lane = t & 63;
        for (int bin = wid; bin < NBINS; bin += 4) {
            int c = hist[bin];
            int g = base[bin];
            int p = pfx[bin];
            for (int l = lane; l < c; l += 64) {
                int slot = g + l;
                if (slot < BIN_CAP)
                    binned[(size_t)bin * BIN_CAP + slot] = staging[p + l];
            }
        }
    }
}

// ---------------------------------------------------------------------------
// S2 fine sort: one block per bin, 1024 threads. Streams the bin's packed
// edges (coalesced) and distributes into node*SLOTS buckets via LDS cursors.
// Writes cnt[] for every node -> no cnt memset.
// ---------------------------------------------------------------------------
__global__ __launch_bounds__(1024) void s2_fine(
        const int* __restrict__ gcnt, const int2* __restrict__ binned,
        int* __restrict__ cnt, int2* __restrict__ buckets) {
    __shared__ int cursor[BIN_W];
    const int bin = blockIdx.x;
    const int t   = threadIdx.x;
    if (t < BIN_W) cursor[t] = 0;
    __syncthreads();

    int m = gcnt[bin]; if (m > BIN_CAP) m = BIN_CAP;
    const int2* bp = &binned[(size_t)bin * BIN_CAP];
    for (int i = t; i < m; i += 1024) {
        int2 p  = bp[i];
        int  dl = ((unsigned)p.x) >> 18;
        int  local = atomicAdd(&cursor[dl], 1);
        if (local < SLOTS) {
            int node = (bin << BIN_SHIFT) + dl;
            buckets[(size_t)node * SLOTS + local] =
                make_int2(p.x & 0x3FFFF, p.y);
        }
    }
    __syncthreads();

    if (t < BIN_W) {
        int node = (bin << BIN_SHIFT) + t;
        if (node < N_NODES) {
            int c = cursor[t]; if (c > SLOTS) c = SLOTS;
            cnt[node] = c;
        }
    }
}

// ---------------------------------------------------------------------------
// bucket SpMM gather, bf16 x/y, f32 accumulate: 8 lanes per dst node,
// ushort8 (16 B) per lane -> 128 B coalesced row gathers; 8 nodes per wave.
// 4 edges/iter, cnt prefetched one node ahead. If list != null, only nodes
// in list[0..count) are computed (last layer: queried rows only).
// ---------------------------------------------------------------------------
__global__ __launch_bounds__(256) void spmm_bucket_bf16(
        const int* __restrict__ cnt, const int2* __restrict__ buckets,
        const unsigned short* __restrict__ x, unsigned short* __restrict__ y,
        const int* __restrict__ list, int count) {
    int lane8   = threadIdx.x & 7;
    int group   = (int)((blockIdx.x * blockDim.x + threadIdx.x) >> 3);
    int ngroups = (int)((gridDim.x * blockDim.x) >> 3);
    const u16x8* x8 = (const u16x8*)x;

    int i = group;
    if (i >= count) return;
    int node_n = list ? list[i] : i;
    int m_n = cnt[node_n];

    for (; i < count; i += ngroups) {
        int node = node_n;
        int m = m_n; if (m > SLOTS) m = SLOTS;
        int j = i + ngroups;
        if (j < count) { node_n = list ? list[j] : j; m_n = cnt[node_n]; }

        const int2* row  = &buckets[(size_t)node * SLOTS];
        const int4* row2 = (const int4*)row;            // 2 packed edges per int4
        float r[8];
        #pragma unroll
        for (int k = 0; k < 8; ++k) r[k] = 0.0f;

        int e = 0;
        for (; e + 4 <= m; e += 4) {
            int4 pa = row2[(e >> 1)];
            int4 pb = row2[(e >> 1) + 1];
            u16x8 x0 = x8[(size_t)pa.x * 8 + lane8];
            u16x8 x1 = x8[(size_t)pa.z * 8 + lane8];
            u16x8 x2 = x8[(size_t)pb.x * 8 + lane8];
            u16x8 x3 = x8[(size_t)pb.z * 8 + lane8];
            float v0 = __int_as_float(pa.y), v1 = __int_as_float(pa.w);
            float v2 = __int_as_float(pb.y), v3 = __int_as_float(pb.w);
            #pragma unroll
            for (int k = 0; k < 8; ++k) r[k] += v0 * bf2f(x0[k]);
            #pragma unroll
            for (int k = 0; k < 8; ++k) r[k] += v1 * bf2f(x1[k]);
            #pragma unroll
            for (int k = 0; k < 8; ++k) r[k] += v2 * bf2f(x2[k]);
            #pragma unroll
            for (int k = 0; k < 8; ++k) r[k] += v3 * bf2f(x3[k]);
        }
        if (e + 2 <= m) {                               // e is even here
            int4 pa = row2[(e >> 1)];
            u16x8 x0 = x8[(size_t)pa.x * 8 + lane8];
            u16x8 x1 = x8[(size_t)pa.z * 8 + lane8];
            float v0 = __int_as_float(pa.y), v1 = __int_as_float(pa.w);
            #pragma unroll
            for (int k = 0; k < 8; ++k) r[k] += v0 * bf2f(x0[k]);
            #pragma unroll
            for (int k = 0; k < 8; ++k) r[k] += v1 * bf2f(x1[k]);
            e += 2;
        }
        if (e < m) {
            int2 p = row[e];
            float v = __int_as_float(p.y);
            u16x8 x0 = x8[(size_t)p.x * 8 + lane8];
            #pragma unroll
            for (int k = 0; k < 8; ++k) r[k] += v * bf2f(x0[k]);
        }

        u16x8 o;
        #pragma unroll
        for (int k = 0; k < 8; ++k) o[k] = (unsigned short)f2bf(r[k]);
        ((u16x8*)y)[(size_t)node * 8 + lane8] = o;
    }
}

// ---------------------------------------------------------------------------
// prep: packed[q] = bf16( (e0 + h1 + h2 + h3) * 0.25 ) for all 21024 queried
// positions (users first, then items). 8 lanes per row, 8 dims per lane.
// ---------------------------------------------------------------------------
__global__ __launch_bounds__(256) void prep_packed(
        const float* __restrict__ ue, const float* __restrict__ ie,
        const unsigned short* __restrict__ h1, const unsigned short* __restrict__ h2,
        const unsigned short* __restrict__ h3, const int* __restrict__ users,
        const int* __restrict__ items, unsigned short* __restrict__ packed) {
    int idx = blockIdx.x * blockDim.x + threadIdx.x;
    if (idx >= N_QTOT * 8) return;
    int q = idx >> 3, lane = idx & 7;

    const float* e0;
    size_t hoff;
    if (q < N_QU) {
        int u = users[q];
        e0   = &ue[(size_t)u * DIM];
        hoff = (size_t)u * DIM;
    } else {
        int it = items[q - N_QU];
        e0   = &ie[(size_t)it * DIM];
        hoff = (size_t)(NUM_USERS + it) * DIM;
    }
    int d0 = lane * 8;
    const float4* s0 = (const float4*)&e0[d0];
    float4 a0 = s0[0], a1 = s0[1];
    u16x8 b1 = *(const u16x8*)&h1[hoff + d0];
    u16x8 b2 = *(const u16x8*)&h2[hoff + d0];
    u16x8 b3 = *(const u16x8*)&h3[hoff + d0];

    float v[8];
    v[0] = a0.x; v[1] = a0.y; v[2] = a0.z; v[3] = a0.w;
    v[4] = a1.x; v[5] = a1.y; v[6] = a1.z; v[7] = a1.w;
    u16x8 o;
    #pragma unroll
    for (int k = 0; k < 8; ++k) {
        float t = (v[k] + bf2f(b1[k]) + bf2f(b2[k]) + bf2f(b3[k])) * 0.25f;
        o[k] = (unsigned short)f2bf(t);
    }
    *(u16x8*)&packed[(size_t)q * DIM + d0] = o;
}

// ---------------------------------------------------------------------------
// ratings = sigmoid( packedU @ packedT^T ) via bf16 MFMA.
// ---------------------------------------------------------------------------
__global__ __launch_bounds__(256) void rating_mfma(
        const unsigned short* __restrict__ packed, float* __restrict__ out) {
    __shared__ short Ut[64 * 72];     //  9216 B
    __shared__ short Tt[256 * 72];    // 36864 B
    const int bj = blockIdx.x;        // item tile (256 wide)
    const int bi = blockIdx.y;        // user tile (64 wide)
    const int tid = threadIdx.x;

    {
        int r = tid >> 2, c16 = (tid & 3) * 16;
        const bf16x8* s = (const bf16x8*)&packed[(size_t)(bi * 64 + r) * DIM + c16];
        *(bf16x8*)&Ut[r * 72 + c16]     = s[0];
        *(bf16x8*)&Ut[r * 72 + c16 + 8] = s[1];
    }

    #pragma unroll
    for (int p = 0; p < 4; ++p) {
        int r = (tid >> 2) + p * 64, c16 = (tid & 3) * 16;
        int jg = bj * 256 + r;
        bf16x8 lo = (bf16x8)(short)0, hi = (bf16x8)(short)0;
        if (jg < N_QI) {
            const bf16x8* s = (const bf16x8*)&packed[(size_t)(N_QU + jg) * DIM + c16];
            lo = s[0]; hi = s[1];
        }
        *(bf16x8*)&Tt[r * 72 + c16]     = lo;
        *(bf16x8*)&Tt[r * 72 + c16 + 8] = hi;
    }
    __syncthreads();

    const int wv = tid >> 6, lane = tid & 63;
    const int lr = lane & 15, kq = lane >> 4;

    f32x4 c[4][4];
    #pragma unroll
    for (int mr = 0; mr < 4; ++mr)
        #pragma unroll
        for (int nr = 0; nr < 4; ++nr)
            c[mr][nr] = (f32x4)(0.0f);

    #pragma unroll
    for (int kb = 0; kb < 2; ++kb) {
        bf16x8 a[4], b[4];
        #pragma unroll
        for (int mr = 0; mr < 4; ++mr)
            a[mr] = *(const bf16x8*)&Ut[(mr * 16 + lr) * 72 + (kb * 4 + kq) * 8];
        #pragma unroll
        for (int nr = 0; nr < 4; ++nr)
            b[nr] = *(const bf16x8*)&Tt[(wv * 64 + nr * 16 + lr) * 72 + (kb * 4 + kq) * 8];
        #pragma unroll
        for (int mr = 0; mr < 4; ++mr)
            #pragma unroll
            for (int nr = 0; nr < 4; ++nr)
                c[mr][nr] = __builtin_amdgcn_mfma_f32_16x16x32_bf16(a[mr], b[nr], c[mr][nr], 0, 0, 0);
    }

    #pragma unroll
    for (int mr = 0; mr < 4; ++mr) {
        int rowg = bi * 64 + mr * 16 + kq * 4;
        #pragma unroll
        for (int nr = 0; nr < 4; ++nr) {
            int colg = bj * 256 + wv * 64 + nr * 16 + lr;
            if (colg < N_QI) {
                #pragma unroll
                for (int q = 0; q < 4; ++q) {
                    float z = c[mr][nr][q];
                    out[(size_t)(rowg + q) * N_QI + colg] = 1.0f / (1.0f + __expf(-z));
                }
            }
        }
    }
}

// ---------------------------------------------------------------------------
extern "C" void kernel_launch(void* const* d_in, const int* in_sizes, int n_in,
                              void* d_out, int out_size, void* d_ws, size_t ws_size,
                              hipStream_t stream) {
    const float* user_emb  = (const float*)d_in[0];
    const float* item_emb  = (const float*)d_in[1];
    const int*   edge_src  = (const int*)d_in[2];
    const int*   edge_dst  = (const int*)d_in[3];
    const float* edge_vals = (const float*)d_in[4];
    const int*   users     = (const int*)d_in[5];
    const int*   items     = (const int*)d_in[6];
    float*       out       = (float*)d_out;
    int n_edges = in_sizes[2];

    const size_t nodeElems = (size_t)N_NODES * DIM;   // 9.6M elems

    // workspace: 4 bf16 node buffers + cnt + buckets + qlist + packed + gcnt.
    // binned (41 MB) ALIASES h1..h3 (57.6 MB) -- dead before spmm writes h1.
    unsigned short* h0 = (unsigned short*)d_ws;
    unsigned short* h1 = h0 + nodeElems;
    unsigned short* h2 = h1 + nodeElems;
    unsigned short* h3 = h2 + nodeElems;
    int*  cnt     = (int*)(h3 + nodeElems);           // 150000 ints
    int2* buckets = (int2*)(cnt + N_NODES);           // 12M int2 = 96 MB
    int*  qlist   = (int*)(buckets + (size_t)N_NODES * SLOTS);   // 21024 ints
    unsigned short* packed = (unsigned short*)(qlist + N_QTOT);  // 21024*64 bf16
    int*  gcnt    = (int*)(packed + (size_t)N_QTOT * DIM);       // 293 ints
    int2* binned  = (int2*)h1;                        // scratch alias, 41 MB

    (void)hipMemsetAsync(gcnt, 0, NBINS * sizeof(int), stream);
    init_h0<<<2048, 256, 0, stream>>>(user_emb, item_emb, h0);
    build_qlist<<<(N_QTOT + 255) / 256, 256, 0, stream>>>(users, items, qlist);

    // two-level CSR build: LDS-sorted coarse bins -> fine LDS sort
    int nbatches = (n_edges + S1_BATCH - 1) / S1_BATCH;
    s1_coarse<<<nbatches, 256, 0, stream>>>(edge_src, edge_dst, edge_vals,
                                            gcnt, binned, n_edges);
    s2_fine<<<NBINS, 1024, 0, stream>>>(gcnt, binned, cnt, buckets);

    spmm_bucket_bf16<<<2048, 256, 0, stream>>>(cnt, buckets, h0, h1, nullptr, N_NODES);
    spmm_bucket_bf16<<<2048, 256, 0, stream>>>(cnt, buckets, h1, h2, nullptr, N_NODES);
    spmm_bucket_bf16<<<2048, 256, 0, stream>>>(cnt, buckets, h2, h3, qlist, N_QTOT);

    prep_packed<<<(N_QTOT * 8 + 255) / 256, 256, 0, stream>>>(
        user_emb, item_emb, h1, h2, h3, users, items, packed);

    dim3 grid((N_QI + 255) / 256, N_QU / 64);
    rating_mfma<<<grid, 256, 0, stream>>>(packed, out);
}